// Round 5
// baseline (74.500 us; speedup 1.0000x reference)
//
#include <hip/hip_runtime.h>

#define B_SIZE 4096
#define IN_F   8192
#define OUT_W  8194           // IN_F + 2 after slicing off the 2-pads
#define ROWS   16             // rows per block (8 even/odd pairs)
#define CHUNKS 4              // column chunks (grid.x), 2048 cols each

typedef float f32x4 __attribute__((ext_vector_type(4)));
typedef float f32x2 __attribute__((ext_vector_type(2)));

// ---------------------------------------------------------------------------
// Kernel 1: gather band coeffs, 4 threads per output column j in [0, IN_F):
//   d=0..2: coeff[j][d] = W[j+2, j+d]  (0 if j+d >= IN_F)
//   d=3   : coeff[j][3] = count(j+2) * bias[j+2]
// ---------------------------------------------------------------------------
__global__ __launch_bounds__(64) void coeff_kernel(
    const float* __restrict__ w, const float* __restrict__ bias,
    float* __restrict__ coeff) {
  const int gid = blockIdx.x * 64 + threadIdx.x;   // [0, 4*IN_F)
  const int j = gid >> 2;
  const int d = gid & 3;
  const size_t c = (size_t)j + 2;
  float v;
  if (d == 3) {
    const float cnt = 1.f + (j + 1 < IN_F ? 1.f : 0.f) + (j + 2 < IN_F ? 1.f : 0.f);
    v = cnt * bias[c];
  } else {
    v = (j + d < IN_F) ? w[c * IN_F + j + d] : 0.f;
  }
  coeff[4 * (size_t)j + d] = v;
}

// ---------------------------------------------------------------------------
// Kernel 2: streaming 3-tap band apply, 8 columns per thread.
//   Per row pair: even row loads x[j..j+9] (2x float4 + guarded float2),
//   odd row loads x[j-2..j+7] (guarded float2 + 2x float4) — no high halo.
//   Row-parity windows keep every out-store an aligned float4:
//     even rows -> cols j..j+7, odd rows -> cols j-2..j+5.
//   Tail thread (j=8184): k6/k7 = coeff[8190/8191] already carry zeros for
//   taps past x[8191]; adds cols 8192..8193 (zeros) on even rows and cols
//   8190..8193 on odd rows.
// ---------------------------------------------------------------------------
__global__ __launch_bounds__(256) void band_kernel(
    const float* __restrict__ x, const float4* __restrict__ coeff,
    float* __restrict__ out) {
  const int t = threadIdx.x;
  const int j = (blockIdx.x * 256 + t) * 8;          // [0, 8192) step 8

  float4 k[8];
#pragma unroll
  for (int q = 0; q < 8; ++q) k[q] = coeff[j + q];
  float4 km2 = make_float4(0.f, 0.f, 0.f, 0.f);
  float4 km1 = make_float4(0.f, 0.f, 0.f, 0.f);
  if (j > 0) { km2 = coeff[j - 2]; km1 = coeff[j - 1]; }

  const bool ghalo = (j + 8 < IN_F);                 // false only for j=8184
  const bool gm    = (j > 0);
  const bool tail  = (j == IN_F - 8);                // global last thread
  const int row0 = blockIdx.y * ROWS;

#pragma unroll 2
  for (int p = 0; p < ROWS / 2; ++p) {
    const size_t r0 = (size_t)(row0 + 2 * p);        // even row
    const size_t r1 = r0 + 1;                        // odd row
    const float* xr0 = x + r0 * (size_t)IN_F;
    const float* xr1 = x + r1 * (size_t)IN_F;

    const f32x4 a0 = *reinterpret_cast<const f32x4*>(xr0 + j);
    const f32x4 b0 = *reinterpret_cast<const f32x4*>(xr0 + j + 4);
    const f32x2 h0 = ghalo ? *reinterpret_cast<const f32x2*>(xr0 + j + 8)
                           : (f32x2){0.f, 0.f};
    const f32x2 m1 = gm ? *reinterpret_cast<const f32x2*>(xr1 + j - 2)
                        : (f32x2){0.f, 0.f};
    const f32x4 a1 = *reinterpret_cast<const f32x4*>(xr1 + j);
    const f32x4 b1 = *reinterpret_cast<const f32x4*>(xr1 + j + 4);

    // even row: cols j..j+7 from x[j..j+9]
    const float o0 = fmaf(k[0].x, a0.x, fmaf(k[0].y, a0.y, fmaf(k[0].z, a0.z, k[0].w)));
    const float o1 = fmaf(k[1].x, a0.y, fmaf(k[1].y, a0.z, fmaf(k[1].z, a0.w, k[1].w)));
    const float o2 = fmaf(k[2].x, a0.z, fmaf(k[2].y, a0.w, fmaf(k[2].z, b0.x, k[2].w)));
    const float o3 = fmaf(k[3].x, a0.w, fmaf(k[3].y, b0.x, fmaf(k[3].z, b0.y, k[3].w)));
    const float o4 = fmaf(k[4].x, b0.x, fmaf(k[4].y, b0.y, fmaf(k[4].z, b0.z, k[4].w)));
    const float o5 = fmaf(k[5].x, b0.y, fmaf(k[5].y, b0.z, fmaf(k[5].z, b0.w, k[5].w)));
    const float o6 = fmaf(k[6].x, b0.z, fmaf(k[6].y, b0.w, fmaf(k[6].z, h0.x, k[6].w)));
    const float o7 = fmaf(k[7].x, b0.w, fmaf(k[7].y, h0.x, fmaf(k[7].z, h0.y, k[7].w)));
    float* orow0 = out + r0 * (size_t)OUT_W + j;
    __builtin_nontemporal_store((f32x4){o0, o1, o2, o3}, reinterpret_cast<f32x4*>(orow0));
    __builtin_nontemporal_store((f32x4){o4, o5, o6, o7}, reinterpret_cast<f32x4*>(orow0 + 4));

    // odd row: cols j-2..j+5 from x[j-2..j+7]
    const float q0 = fmaf(km2.x, m1.x, fmaf(km2.y, m1.y, fmaf(km2.z, a1.x, km2.w)));
    const float q1 = fmaf(km1.x, m1.y, fmaf(km1.y, a1.x, fmaf(km1.z, a1.y, km1.w)));
    const float q2 = fmaf(k[0].x, a1.x, fmaf(k[0].y, a1.y, fmaf(k[0].z, a1.z, k[0].w)));
    const float q3 = fmaf(k[1].x, a1.y, fmaf(k[1].y, a1.z, fmaf(k[1].z, a1.w, k[1].w)));
    const float q4 = fmaf(k[2].x, a1.z, fmaf(k[2].y, a1.w, fmaf(k[2].z, b1.x, k[2].w)));
    const float q5 = fmaf(k[3].x, a1.w, fmaf(k[3].y, b1.x, fmaf(k[3].z, b1.y, k[3].w)));
    const float q6 = fmaf(k[4].x, b1.x, fmaf(k[4].y, b1.y, fmaf(k[4].z, b1.z, k[4].w)));
    const float q7 = fmaf(k[5].x, b1.y, fmaf(k[5].y, b1.z, fmaf(k[5].z, b1.w, k[5].w)));
    float* orow1 = out + r1 * (size_t)OUT_W + j;
    if (gm) {
      __builtin_nontemporal_store((f32x4){q0, q1, q2, q3}, reinterpret_cast<f32x4*>(orow1 - 2));
    } else {
      __builtin_nontemporal_store((f32x2){q2, q3}, reinterpret_cast<f32x2*>(orow1));
    }
    __builtin_nontemporal_store((f32x4){q4, q5, q6, q7}, reinterpret_cast<f32x4*>(orow1 + 2));

    if (tail) {
      // even row: cols 8192..8193 are exact zeros
      __builtin_nontemporal_store((f32x2){0.f, 0.f},
          reinterpret_cast<f32x2*>(orow0 + 8));
      // odd row: cols 8190..8193 (k[6].z = k[7].y = k[7].z = 0 baked)
      const float t0 = fmaf(k[6].x, b1.z, fmaf(k[6].y, b1.w, k[6].w));
      const float t1 = fmaf(k[7].x, b1.w, k[7].w);
      __builtin_nontemporal_store((f32x4){t0, t1, 0.f, 0.f},
          reinterpret_cast<f32x4*>(orow1 + 6));
    }
  }
}

extern "C" void kernel_launch(void* const* d_in, const int* in_sizes, int n_in,
                              void* d_out, int out_size, void* d_ws, size_t ws_size,
                              hipStream_t stream) {
  const float* x    = (const float*)d_in[0];   // [4096, 8192]
  const float* w    = (const float*)d_in[1];   // [8198, 8192]
  const float* bias = (const float*)d_in[2];   // [8198]
  float* out = (float*)d_out;                  // [4096, 8194]
  float* coeff = (float*)d_ws;                 // IN_F * 16 B = 128 KB scratch

  coeff_kernel<<<(4 * IN_F) / 64, 64, 0, stream>>>(w, bias, coeff);

  dim3 grid(CHUNKS, B_SIZE / ROWS);            // 4 x 256 = 1024 blocks
  band_kernel<<<grid, 256, 0, stream>>>(x, (const float4*)coeff, out);
}

// Round 6
// 53.252 us; speedup vs baseline: 1.3990x; 1.3990x over previous
//
#include <hip/hip_runtime.h>

#define B_SIZE 4096
#define IN_F   8192
#define OUT_W  8194           // IN_F + 2 after slicing off the 2-pads
#define ROWS   16             // rows per block
#define CHUNKS 8              // column chunks (grid.x), 1024 cols each

typedef float f32x4 __attribute__((ext_vector_type(4)));
typedef float f32x2 __attribute__((ext_vector_type(2)));

// ---------------------------------------------------------------------------
// Kernel 1: gather band coeffs, 4 threads per output column j in [0, IN_F):
//   d=0..2: coeff[j][d] = W[j+2, j+d]  (0 if j+d >= IN_F)
//   d=3   : coeff[j][3] = count(j+2) * bias[j+2]
// 32K threads across 512 blocks -> all ~25K scattered W cachelines fetched
// in one HBM latency round.
// ---------------------------------------------------------------------------
__global__ __launch_bounds__(64) void coeff_kernel(
    const float* __restrict__ w, const float* __restrict__ bias,
    float* __restrict__ coeff) {
  const int gid = blockIdx.x * 64 + threadIdx.x;   // [0, 4*IN_F)
  const int j = gid >> 2;
  const int d = gid & 3;
  const size_t c = (size_t)j + 2;
  float v;
  if (d == 3) {
    const float cnt = 1.f + (j + 1 < IN_F ? 1.f : 0.f) + (j + 2 < IN_F ? 1.f : 0.f);
    v = cnt * bias[c];
  } else {
    v = (j + d < IN_F) ? w[c * IN_F + j + d] : 0.f;
  }
  coeff[4 * (size_t)j + d] = v;
}

// ---------------------------------------------------------------------------
// Kernel 2: streaming 3-tap band apply (proven R3 structure, 53.2 us).
//   Thread owns 4 consecutive columns (wave loads 1024B contiguous — R5
//   showed wider per-thread ownership breaks wave coalescing and regresses).
//   Coeffs in registers; per row: one float4 x-load + one guarded float2
//   halo load (L1-hit, same lines), two nontemporal float2 stores (row
//   byte stride 32776 is 8-mod-16; store width proved neutral in R4).
// ---------------------------------------------------------------------------
__global__ __launch_bounds__(256) void band_kernel(
    const float* __restrict__ x, const float4* __restrict__ coeff,
    float* __restrict__ out) {
  const int j = (blockIdx.x * 256 + threadIdx.x) * 4;   // [0, 8192) step 4
  const float4 k0 = coeff[j];
  const float4 k1 = coeff[j + 1];
  const float4 k2 = coeff[j + 2];
  const float4 k3 = coeff[j + 3];
  const bool ghalo = (j + 4 < IN_F);       // false only for the last thread
  const bool tail = (blockIdx.x == CHUNKS - 1) && (threadIdx.x == 255);
  const int row0 = blockIdx.y * ROWS;

#pragma unroll 4
  for (int r = 0; r < ROWS; ++r) {
    const size_t row = (size_t)(row0 + r);
    const float* xr = x + row * (size_t)IN_F;
    const f32x4 xv = *reinterpret_cast<const f32x4*>(xr + j);   // 16B aligned
    const f32x2 xh = ghalo ? *reinterpret_cast<const f32x2*>(xr + j + 4)
                           : (f32x2){0.f, 0.f};                 // 8B aligned
    const float o0 = fmaf(k0.x, xv.x, fmaf(k0.y, xv.y, fmaf(k0.z, xv.z, k0.w)));
    const float o1 = fmaf(k1.x, xv.y, fmaf(k1.y, xv.z, fmaf(k1.z, xv.w, k1.w)));
    const float o2 = fmaf(k2.x, xv.z, fmaf(k2.y, xv.w, fmaf(k2.z, xh.x, k2.w)));
    const float o3 = fmaf(k3.x, xv.w, fmaf(k3.y, xh.x, fmaf(k3.z, xh.y, k3.w)));
    float* orow = out + row * (size_t)OUT_W + j;
    __builtin_nontemporal_store((f32x2){o0, o1}, reinterpret_cast<f32x2*>(orow));
    __builtin_nontemporal_store((f32x2){o2, o3}, reinterpret_cast<f32x2*>(orow + 2));
    if (tail) {                            // columns 8192..8193 are exact zeros
      __builtin_nontemporal_store((f32x2){0.f, 0.f},
          reinterpret_cast<f32x2*>(out + row * (size_t)OUT_W + IN_F));
    }
  }
}

extern "C" void kernel_launch(void* const* d_in, const int* in_sizes, int n_in,
                              void* d_out, int out_size, void* d_ws, size_t ws_size,
                              hipStream_t stream) {
  const float* x    = (const float*)d_in[0];   // [4096, 8192]
  const float* w    = (const float*)d_in[1];   // [8198, 8192]
  const float* bias = (const float*)d_in[2];   // [8198]
  float* out = (float*)d_out;                  // [4096, 8194]
  float* coeff = (float*)d_ws;                 // IN_F * 16 B = 128 KB scratch

  coeff_kernel<<<(4 * IN_F) / 64, 64, 0, stream>>>(w, bias, coeff);

  dim3 grid(CHUNKS, B_SIZE / ROWS);            // 8 x 256 = 2048 blocks
  band_kernel<<<grid, 256, 0, stream>>>(x, (const float4*)coeff, out);
}